// Round 2
// baseline (2520.803 us; speedup 1.0000x reference)
//
#include <hip/hip_runtime.h>
#include <math.h>

#define NTOK 131072
#define HDIM 256
#define DDIM 512
#define FDIM 1024
#define EDIM 16
#define TBLK 128
#define FCH  128
#define KCH  32
#define XST  132   // 132*4 = 528 B row stride: 16B-aligned, conflict-light

__global__ __launch_bounds__(256, 4)
void router_fused(const float* __restrict__ inp,
                  const float* __restrict__ cnd,
                  const float* __restrict__ W1,
                  const float* __restrict__ b1,
                  const float* __restrict__ W2,
                  const float* __restrict__ b2,
                  float* __restrict__ out)
{
    __shared__ float xs[KCH][XST];   // x tile, k-major: xs[k][t]
    __shared__ float w1s[KCH][FCH];  // W1 tile: w1s[k][f]

    const int tid = threadIdx.x;
    const int ty  = tid >> 4;   // 0..15: token group (8 tokens each)
    const int tx  = tid & 15;   // 0..15: f-cols {tx*4..+3, 64+tx*4..+3}; expert lane in epilogue
    const int t0  = blockIdx.x * TBLK;

    // running logits: lane tx owns expert tx for its 8 tokens
    float lg[8];
    {
        const float bb = b2[tx];
#pragma unroll
        for (int i = 0; i < 8; ++i) lg[i] = bb;
    }

    for (int fc = 0; fc < FDIM; fc += FCH) {
        float acc[8][8];
#pragma unroll
        for (int i = 0; i < 8; ++i)
#pragma unroll
            for (int j = 0; j < 8; ++j) acc[i][j] = 0.0f;

        for (int kc = 0; kc < DDIM; kc += KCH) {
            __syncthreads();
            // ---- stage x tile (transpose into xs[k][t]) ----
            {
                const float* src = (kc < HDIM)
                    ? (inp + (size_t)t0 * HDIM + kc)
                    : (cnd + (size_t)t0 * HDIM + (kc - HDIM));
                const int kl = (tid & 7) * 4;   // 0..28
                const int tl = tid >> 3;        // 0..31
#pragma unroll
                for (int p = 0; p < 4; ++p) {
                    const int trow = tl + p * 32;
                    const float4 v = *(const float4*)(src + (size_t)trow * HDIM + kl);
                    xs[kl + 0][trow] = v.x;
                    xs[kl + 1][trow] = v.y;
                    xs[kl + 2][trow] = v.z;
                    xs[kl + 3][trow] = v.w;
                }
            }
            // ---- stage W1 tile ----
            {
                const int fl = (tid & 31) * 4;  // 0..124
                const int kr = tid >> 5;        // 0..7
#pragma unroll
                for (int p = 0; p < 4; ++p)
                    *(float4*)&w1s[kr + p * 8][fl] =
                        *(const float4*)(W1 + (size_t)(kc + kr + p * 8) * FDIM + fc + fl);
            }
            __syncthreads();
            // ---- 128x128x32 register-blocked FMA ----
#pragma unroll 8
            for (int k = 0; k < KCH; ++k) {
                const float4 a0 = *(const float4*)&xs[k][ty * 8];
                const float4 a1 = *(const float4*)&xs[k][ty * 8 + 4];
                const float4 b0 = *(const float4*)&w1s[k][tx * 4];
                const float4 b4 = *(const float4*)&w1s[k][64 + tx * 4];
                const float av[8] = {a0.x, a0.y, a0.z, a0.w, a1.x, a1.y, a1.z, a1.w};
                const float bv[8] = {b0.x, b0.y, b0.z, b0.w, b4.x, b4.y, b4.z, b4.w};
#pragma unroll
                for (int i = 0; i < 8; ++i)
#pragma unroll
                    for (int j = 0; j < 8; ++j)
                        acc[i][j] = fmaf(av[i], bv[j], acc[i][j]);
            }
        }

        // ---- bias + exact GELU ----
        {
            const float4 ba = *(const float4*)(b1 + fc + tx * 4);
            const float4 bc = *(const float4*)(b1 + fc + 64 + tx * 4);
            const float bias[8] = {ba.x, ba.y, ba.z, ba.w, bc.x, bc.y, bc.z, bc.w};
#pragma unroll
            for (int i = 0; i < 8; ++i)
#pragma unroll
                for (int j = 0; j < 8; ++j) {
                    const float v = acc[i][j] + bias[j];
                    acc[i][j] = 0.5f * v * (1.0f + erff(v * 0.70710678118654752f));
                }
        }

        // ---- GEMM2 partial logits + deterministic 16-lane butterfly reduce ----
#pragma unroll
        for (int q = 0; q < 4; ++q) {
            float w2q[8][4];
#pragma unroll
            for (int j = 0; j < 8; ++j) {
                const int f = fc + ((j < 4) ? (tx * 4 + j) : (64 + tx * 4 + (j - 4)));
                const float4 w = *(const float4*)(W2 + (size_t)f * EDIM + q * 4);
                w2q[j][0] = w.x; w2q[j][1] = w.y; w2q[j][2] = w.z; w2q[j][3] = w.w;
            }
#pragma unroll
            for (int i = 0; i < 8; ++i) {
                float pe[4] = {0.0f, 0.0f, 0.0f, 0.0f};
#pragma unroll
                for (int j = 0; j < 8; ++j)
#pragma unroll
                    for (int e = 0; e < 4; ++e)
                        pe[e] = fmaf(acc[i][j], w2q[j][e], pe[e]);
#pragma unroll
                for (int m = 1; m < 16; m <<= 1)
#pragma unroll
                    for (int e = 0; e < 4; ++e)
                        pe[e] += __shfl_xor(pe[e], m, 64);
                if ((tx >> 2) == q) lg[i] += pe[tx & 3];
            }
        }
    }

    // ---- softmax + clip + top-2 + writes: lane tx = expert tx, tokens ty*8+i ----
#pragma unroll
    for (int i = 0; i < 8; ++i) {
        const int t = t0 + ty * 8 + i;
        // max over experts (16-lane butterfly)
        float mx = lg[i];
#pragma unroll
        for (int m = 1; m < 16; m <<= 1) mx = fmaxf(mx, __shfl_xor(mx, m, 64));
        float p = expf(lg[i] - mx);
        float s = p;
#pragma unroll
        for (int m = 1; m < 16; m <<= 1) s += __shfl_xor(s, m, 64);
        float pr = p / s;
        pr = fminf(fmaxf(pr, 1e-9f), 1.0f - 1e-9f);

        // top-1: max value, lowest index on ties
        float v1 = pr; int i1 = tx;
#pragma unroll
        for (int m = 1; m < 16; m <<= 1) {
            const float vo = __shfl_xor(v1, m, 64);
            const int   io = __shfl_xor(i1, m, 64);
            if (vo > v1 || (vo == v1 && io < i1)) { v1 = vo; i1 = io; }
        }
        // top-2: exclude i1
        float v2 = (tx == i1) ? -1.0f : pr; int i2 = tx;
#pragma unroll
        for (int m = 1; m < 16; m <<= 1) {
            const float vo = __shfl_xor(v2, m, 64);
            const int   io = __shfl_xor(i2, m, 64);
            if (vo > v2 || (vo == v2 && io < i2)) { v2 = vo; i2 = io; }
        }
        const float rs = 1.0f / (v1 + v2);

        float* om  = out + (size_t)t * EDIM;
        float* orp = out + (size_t)NTOK * 18 + (size_t)t * EDIM;
        float* opf = out + (size_t)NTOK * 34 + (size_t)t * EDIM;
        om[tx]  = (tx == i1 || tx == i2) ? 1.0f : 0.0f;
        orp[tx] = (tx == i1) ? v1 * rs : ((tx == i2) ? v2 * rs : 0.0f);
        opf[tx] = pr;
        if (tx == 0) {
            float2* oi = (float2*)(out + (size_t)NTOK * 16 + (size_t)t * 2);
            *oi = make_float2((float)i1, (float)i2);
        }
    }
}

extern "C" void kernel_launch(void* const* d_in, const int* in_sizes, int n_in,
                              void* d_out, int out_size, void* d_ws, size_t ws_size,
                              hipStream_t stream)
{
    const float* inp = (const float*)d_in[0];
    const float* cnd = (const float*)d_in[1];
    const float* W1  = (const float*)d_in[2];
    const float* b1  = (const float*)d_in[3];
    const float* W2  = (const float*)d_in[4];
    const float* b2  = (const float*)d_in[5];
    float* out = (float*)d_out;

    dim3 grid(NTOK / TBLK), block(256);
    hipLaunchKernelGGL(router_fused, grid, block, 0, stream,
                       inp, cnd, W1, b1, W2, b2, out);
}